// Round 6
// baseline (445.885 us; speedup 1.0000x reference)
//
#include <hip/hip_runtime.h>
#include <stdint.h>

typedef unsigned short u16;
typedef unsigned int   u32;
typedef _Float16 f16;
typedef __attribute__((ext_vector_type(4))) float    f32x4;
typedef __attribute__((ext_vector_type(8))) _Float16 f16x8;
typedef __attribute__((ext_vector_type(4))) _Float16 f16x4;

#define DIM    1024
#define NROWS  8192
#define NLAYER 10
#define NBLK   256

__device__ __forceinline__ void gl_lds16(const void* g, void* l) {
    __builtin_amdgcn_global_load_lds((const __attribute__((address_space(1))) u32*)g,
                                     (__attribute__((address_space(3))) u32*)l, 16, 0, 0);
}

// ---------- conversion: f32 -> f16 plane ----------
__global__ __launch_bounds__(256) void conv_weights(const float* __restrict__ W0,
                                                    const float* __restrict__ Wh,
                                                    f16* __restrict__ Wf) {
    int i = (blockIdx.x * 256 + threadIdx.x) * 4;   // covers 10*1024*1024
    const float* src = (i < 1048576) ? (W0 + i) : (Wh + (i - 1048576));
    float4 w = *(const float4*)src;
    f16x4 o;
    o.x = (f16)w.x; o.y = (f16)w.y; o.z = (f16)w.z; o.w = (f16)w.w;
    *(f16x4*)(Wf + i) = o;
}

__global__ __launch_bounds__(256) void conv_x(const float* __restrict__ x,
                                              f16* __restrict__ Af) {
    int i = (blockIdx.x * 256 + threadIdx.x) * 4;   // covers 8192*1024
    float4 w = *(const float4*)(x + i);
    f16x4 o;
    o.x = (f16)w.x; o.y = (f16)w.y; o.z = (f16)w.z; o.w = (f16)w.w;
    *(f16x4*)(Af + i) = o;
}

// ---------- persistent mono-kernel: 10 fused layers + output gemv ----------
// BM=256 BN=128 BK=64, 512 threads = 8 waves (4M x 2N), 64x64/wave.
// LDS 96 KB (>80 KB => exactly 1 block/CU => all 256 blocks co-resident,
// software grid barrier is deadlock-free). Layer body = round-2 schedule.
#define ABUF_B 0        // [256][64] f16 = 32 KB
#define BBUF_B 32768    // [128][64] f16 = 16 KB
#define BUFSZ  49152
#define NKT    16

__global__ __launch_bounds__(512, 2) void mono_net(
        const f16* __restrict__ Wf,
        const float* __restrict__ b0,
        const float* __restrict__ bh,
        const float* __restrict__ Wout,
        const float* __restrict__ bout,
        f16* __restrict__ bufA,
        f16* __restrict__ bufB,
        u32* __restrict__ ctr,
        float* __restrict__ out) {
    __shared__ char lds[2 * BUFSZ];   // 96 KB

    // XCD-aware bijective swizzle: 256 blocks, 8 XCDs, 32/XCD
    int bid = blockIdx.x;
    int swz = (bid & 7) * 32 + (bid >> 3);
    int bn = swz & 7;    // 0..7
    int bm = swz >> 3;   // 0..31

    const int tid  = threadIdx.x;
    const int lane = tid & 63;
    const int wid  = tid >> 6;
    const int wr   = wid >> 1;   // 0..3
    const int wc   = wid & 1;    // 0..1

    const int swcol = (((lane & 7) ^ ((lane >> 3) & 7)) << 4);

    for (int l = 0; l < NLAYER; ++l) {
        const f16* Ab = (l & 1) ? bufB : bufA;
        f16*       Ob = (l & 1) ? bufA : bufB;
        const f16* Wb = Wf + (size_t)l * DIM * DIM;
        const float* bias = l ? (bh + (size_t)(l - 1) * DIM) : b0;

        // ---- staging ptrs: 48 chunks of 1KB (8 rows x 128B) per K-tile, 6/wave ----
        const char* gsrc[6];
        u32 ldst[6];
        #pragma unroll
        for (int j = 0; j < 6; ++j) {
            int c = wid * 6 + j;
            if (c < 32) {                       // A chunks
                int grow = bm * 256 + c * 8 + (lane >> 3);
                gsrc[j] = (const char*)Ab + (size_t)grow * 2048 + swcol;
                ldst[j] = ABUF_B + c * 1024;
            } else {                            // B chunks
                int c2 = c - 32;
                int grow = bn * 128 + c2 * 8 + (lane >> 3);
                gsrc[j] = (const char*)Wb + (size_t)grow * 2048 + swcol;
                ldst[j] = BBUF_B + c2 * 1024;
            }
        }

        f32x4 acc[4][4];
        #pragma unroll
        for (int mf = 0; mf < 4; ++mf)
            #pragma unroll
            for (int nf = 0; nf < 4; ++nf)
                acc[mf][nf] = (f32x4){0.f, 0.f, 0.f, 0.f};

        // prologue: stage kt=0 into buffer 0
        #pragma unroll
        for (int j = 0; j < 6; ++j)
            gl_lds16(gsrc[j], lds + ldst[j]);
        __syncthreads();

        for (int kt = 0; kt < NKT; ++kt) {
            const char* base = lds + (kt & 1) * BUFSZ;
            if (kt < NKT - 1) {
                char* nb = lds + ((kt + 1) & 1) * BUFSZ;
                #pragma unroll
                for (int j = 0; j < 6; ++j)
                    gl_lds16(gsrc[j] + (size_t)(kt + 1) * 128, nb + ldst[j]);
            }

            #pragma unroll
            for (int ks = 0; ks < 2; ++ks) {
                f16x8 a[4], b[4];
                const int cb = ks * 64 + ((lane >> 4) << 4);
                #pragma unroll
                for (int mf = 0; mf < 4; ++mf) {
                    int r = wr * 64 + mf * 16 + (lane & 15);
                    int byt = r * 128 + (cb ^ ((r & 7) << 4));
                    a[mf] = *(const f16x8*)(base + ABUF_B + byt);
                }
                #pragma unroll
                for (int nf = 0; nf < 4; ++nf) {
                    int r = wc * 64 + nf * 16 + (lane & 15);
                    int byt = r * 128 + (cb ^ ((r & 7) << 4));
                    b[nf] = *(const f16x8*)(base + BBUF_B + byt);
                }
                __builtin_amdgcn_s_setprio(1);
                #pragma unroll
                for (int mf = 0; mf < 4; ++mf)
                    #pragma unroll
                    for (int nf = 0; nf < 4; ++nf)
                        // swapped operands -> C^T layout (lane holds 4 consecutive cols)
                        acc[mf][nf] = __builtin_amdgcn_mfma_f32_16x16x32_f16(b[nf], a[mf], acc[mf][nf], 0, 0, 0);
                __builtin_amdgcn_s_setprio(0);
            }
            __syncthreads();
        }

        // ---- epilogue: bias + sigmoid -> f16, 8B vector stores ----
        #pragma unroll
        for (int nf = 0; nf < 4; ++nf) {
            int gn0 = bn * 128 + wc * 64 + nf * 16 + ((lane >> 4) << 2);
            f32x4 b4 = *(const f32x4*)(bias + gn0);
            #pragma unroll
            for (int mf = 0; mf < 4; ++mf) {
                int gm = bm * 256 + wr * 64 + mf * 16 + (lane & 15);
                f16x4 o;
                #pragma unroll
                for (int j = 0; j < 4; ++j) {
                    float z = acc[mf][nf][j] + b4[j];
                    o[j] = (f16)(1.0f / (1.0f + __expf(-z)));
                }
                *(f16x4*)(Ob + (size_t)gm * DIM + gn0) = o;
            }
        }

        // ---- grid barrier l (release -> arrive -> spin -> acquire) ----
        __syncthreads();                 // all waves' stores drained (vmcnt 0)
        if (tid == 0) {
            __threadfence();             // release: flush XCD L2 dirty lines
            atomicAdd(&ctr[l * 16], 1u); // device-scope arrive
            while (__hip_atomic_load(&ctr[l * 16], __ATOMIC_RELAXED,
                                     __HIP_MEMORY_SCOPE_AGENT) < NBLK)
                __builtin_amdgcn_s_sleep(2);
            __threadfence();             // acquire: invalidate L1/L2 stale lines
        }
        __syncthreads();
    }

    // ---- output gemv: final h is in bufA (layer 9 wrote Ob=bufA) ----
    // 256 blocks x 32 rows; 8 waves -> 4 passes of 8 rows.
    #pragma unroll
    for (int pass = 0; pass < 4; ++pass) {
        int row = bid * 32 + pass * 8 + wid;
        const f16* p = bufA + (size_t)row * DIM + lane * 16;
        const float* pw = Wout + lane * 16;
        float s = 0.f;
        #pragma unroll
        for (int i = 0; i < 4; ++i) {
            f16x4 h4 = *(const f16x4*)(p + i * 4);
            float4 w4 = *(const float4*)(pw + i * 4);
            s += (float)h4.x * w4.x + (float)h4.y * w4.y + (float)h4.z * w4.z + (float)h4.w * w4.w;
        }
        #pragma unroll
        for (int off = 32; off > 0; off >>= 1)
            s += __shfl_down(s, off);
        if (lane == 0) out[row] = s + bout[0];
    }
}

// ---------- launcher ----------
extern "C" void kernel_launch(void* const* d_in, const int* in_sizes, int n_in,
                              void* d_out, int out_size, void* d_ws, size_t ws_size,
                              hipStream_t stream) {
    const float* x    = (const float*)d_in[0];
    const float* W0   = (const float*)d_in[1];
    const float* b0   = (const float*)d_in[2];
    const float* Wh   = (const float*)d_in[3];
    const float* bh   = (const float*)d_in[4];
    const float* Wout = (const float*)d_in[5];
    const float* bout = (const float*)d_in[6];
    float* out = (float*)d_out;

    f16* ws = (f16*)d_ws;
    f16* Wf = ws;                                  // 10*1024*1024 f16 = 20 MB
    f16* A0 = Wf + (size_t)NLAYER * DIM * DIM;     // 16 MB
    f16* A1 = A0 + (size_t)NROWS * DIM;            // 16 MB
    u32* ctr = (u32*)(A1 + (size_t)NROWS * DIM);   // 10 x 64B counters

    hipMemsetAsync(ctr, 0, NLAYER * 16 * sizeof(u32), stream);
    conv_weights<<<NLAYER * DIM * DIM / 1024, 256, 0, stream>>>(W0, Wh, Wf);
    conv_x<<<NROWS * DIM / 1024, 256, 0, stream>>>(x, A0);

    mono_net<<<NBLK, 512, 0, stream>>>(Wf, b0, bh, Wout, bout, A0, A1, ctr, out);
}

// Round 7
// 316.770 us; speedup vs baseline: 1.4076x; 1.4076x over previous
//
#include <hip/hip_runtime.h>
#include <stdint.h>

typedef unsigned short u16;
typedef unsigned int   u32;
typedef _Float16 f16;
typedef __attribute__((ext_vector_type(4))) float    f32x4;
typedef __attribute__((ext_vector_type(8))) _Float16 f16x8;
typedef __attribute__((ext_vector_type(4))) _Float16 f16x4;

#define DIM    1024
#define NROWS  8192
#define NLAYER 10

__device__ __forceinline__ void gl_lds16(const void* g, void* l) {
    __builtin_amdgcn_global_load_lds((const __attribute__((address_space(1))) u32*)g,
                                     (__attribute__((address_space(3))) u32*)l, 16, 0, 0);
}

__device__ __forceinline__ f16 cvt16(float x) { return (f16)x; }

// ---------- weight conversion: f32 -> fragment-order packed f16 chunks ----------
// Chunk (lz, n16, kc): 1 KB = 64 lanes x 16 B; lane l holds W[n16*16 + (l&15)]
// [kc*32 + (l>>4)*8 .. +7] -- byte-identical to the LDS fragment the GEMM read
// in round 2 (col=lane&15, k=(lane>>4)*8+j). One wave produces one chunk:
// reads 16 rows x 128 B f32 (full cache lines), writes 1 KB coalesced.
__global__ __launch_bounds__(256) void conv_weights(const float* __restrict__ W0,
                                                    const float* __restrict__ Wh,
                                                    f16* __restrict__ Wp) {
    int g    = blockIdx.x * 4 + (threadIdx.x >> 6);   // wave id = chunk id, 20480 total
    int lane = threadIdx.x & 63;
    int lz   = g >> 11;            // layer
    int rem  = g & 2047;
    int n16  = rem >> 5;           // 0..63  (16-row group)
    int kc   = rem & 31;           // 0..31  (K=32 chunk)
    int n  = n16 * 16 + (lane & 15);
    int k0 = kc * 32 + (lane >> 4) * 8;
    const float* src = (lz == 0 ? W0 : Wh + (size_t)(lz - 1) * DIM * DIM) + (size_t)n * DIM + k0;
    float4 w0 = *(const float4*)src;
    float4 w1 = *(const float4*)(src + 4);
    f16x8 o;
    o[0]=cvt16(w0.x); o[1]=cvt16(w0.y); o[2]=cvt16(w0.z); o[3]=cvt16(w0.w);
    o[4]=cvt16(w1.x); o[5]=cvt16(w1.y); o[6]=cvt16(w1.z); o[7]=cvt16(w1.w);
    *(f16x8*)((char*)Wp + (size_t)g * 1024 + lane * 16) = o;
}

__global__ __launch_bounds__(256) void conv_x(const float* __restrict__ x,
                                              f16* __restrict__ Af) {
    int i = (blockIdx.x * 256 + threadIdx.x) * 4;   // covers 8192*1024
    float4 w = *(const float4*)(x + i);
    f16x4 o;
    o.x = (f16)w.x; o.y = (f16)w.y; o.z = (f16)w.z; o.w = (f16)w.w;
    *(f16x4*)(Af + i) = o;
}

// ---------- fused layer: C = A(8192xK) * W^T + bias, sigmoid -> f16 ----------
// BM=256 BN=128 BK=64, 512 threads = 8 waves (4M x 2N), 64x64/wave.
// A: global_load_lds double-buffer (2 x 32 KB, XOR-swizzled). B: DIRECT
// global->register fragment loads from the packed layout (L1/L2-hot, no LDS).
// r2's proven schedule: {b-loads, stage(next A), a-reads, MFMA, __syncthreads}.
#define ABUF  32768
#define NKT   16

__global__ __launch_bounds__(512, 2) void layer_gemm(
        const f16* __restrict__ A,
        const f16* __restrict__ Bp,     // packed weight chunks for this layer
        const float* __restrict__ bias,
        f16* __restrict__ O) {
    __shared__ char lds[2 * ABUF];   // 64 KB (A only)

    // XCD-aware bijective swizzle: 256 blocks, 8 XCDs, 32/XCD
    int bid = blockIdx.x;
    int swz = (bid & 7) * 32 + (bid >> 3);
    int bn = swz & 7;    // 0..7
    int bm = swz >> 3;   // 0..31

    const int tid  = threadIdx.x;
    const int lane = tid & 63;
    const int wid  = tid >> 6;
    const int wr   = wid >> 1;   // 0..3
    const int wc   = wid & 1;    // 0..1

    // ---- A staging: 32 chunks of 1KB (8 rows x 128B) per K-tile, 4 per wave ----
    // pre-swizzled global source; logical (row r, colbyte cb) at LDS r*128 + (cb ^ ((r&7)<<4))
    const int swcol = (((lane & 7) ^ ((lane >> 3) & 7)) << 4);
    const char* gsrc[4];
    u32 ldst[4];
    #pragma unroll
    for (int j = 0; j < 4; ++j) {
        int c = wid * 4 + j;
        int grow = bm * 256 + c * 8 + (lane >> 3);
        gsrc[j] = (const char*)A + (size_t)grow * 2048 + swcol;
        ldst[j] = c * 1024;
    }

    // ---- B fragment base: chunk (n16 = bn*8 + wc*4 + nf, kc = kt*2 + ks) ----
    const char* bptr = (const char*)Bp
                     + ((size_t)(bn * 8 + wc * 4) * 32) * 1024 + lane * 16;

    f32x4 acc[4][4];
    #pragma unroll
    for (int mf = 0; mf < 4; ++mf)
        #pragma unroll
        for (int nf = 0; nf < 4; ++nf)
            acc[mf][nf] = (f32x4){0.f, 0.f, 0.f, 0.f};

    // prologue: stage A kt=0 into buffer 0
    #pragma unroll
    for (int j = 0; j < 4; ++j)
        gl_lds16(gsrc[j], lds + ldst[j]);
    __syncthreads();

    for (int kt = 0; kt < NKT; ++kt) {
        // B fragments for this K-tile: 8 coalesced 1KB wave-loads (L1/L2-hot)
        f16x8 b[2][4];
        #pragma unroll
        for (int ks = 0; ks < 2; ++ks)
            #pragma unroll
            for (int nf = 0; nf < 4; ++nf)
                b[ks][nf] = *(const f16x8*)(bptr + ((size_t)(nf * 32 + kt * 2 + ks)) * 1024);

        // stage next A tile into the other buffer (lands during compute below)
        if (kt < NKT - 1) {
            char* nb = lds + ((kt + 1) & 1) * ABUF;
            #pragma unroll
            for (int j = 0; j < 4; ++j)
                gl_lds16(gsrc[j] + (size_t)(kt + 1) * 128, nb + ldst[j]);
        }

        const char* base = lds + (kt & 1) * ABUF;
        #pragma unroll
        for (int ks = 0; ks < 2; ++ks) {
            f16x8 a[4];
            const int cb = ks * 64 + ((lane >> 4) << 4);
            #pragma unroll
            for (int mf = 0; mf < 4; ++mf) {
                int r = wr * 64 + mf * 16 + (lane & 15);
                int byt = r * 128 + (cb ^ ((r & 7) << 4));
                a[mf] = *(const f16x8*)(base + byt);
            }
            __builtin_amdgcn_s_setprio(1);
            #pragma unroll
            for (int mf = 0; mf < 4; ++mf)
                #pragma unroll
                for (int nf = 0; nf < 4; ++nf)
                    // swapped operands -> C^T layout (lane holds 4 consecutive cols)
                    acc[mf][nf] = __builtin_amdgcn_mfma_f32_16x16x32_f16(b[ks][nf], a[mf], acc[mf][nf], 0, 0, 0);
            __builtin_amdgcn_s_setprio(0);
        }
        __syncthreads();   // reads of cur done + next-tile stage drained
    }

    // ---- epilogue: bias + sigmoid -> f16, 8B vector stores ----
    // swapped layout: lane holds rows gm = mf*16+(lane&15), cols gn0..gn0+3
    #pragma unroll
    for (int nf = 0; nf < 4; ++nf) {
        int gn0 = bn * 128 + wc * 64 + nf * 16 + ((lane >> 4) << 2);
        f32x4 b4 = *(const f32x4*)(bias + gn0);
        #pragma unroll
        for (int mf = 0; mf < 4; ++mf) {
            int gm = bm * 256 + wr * 64 + mf * 16 + (lane & 15);
            f16x4 o;
            #pragma unroll
            for (int j = 0; j < 4; ++j) {
                float z = acc[mf][nf][j] + b4[j];
                o[j] = (f16)(1.0f / (1.0f + __expf(-z)));
            }
            *(f16x4*)(O + (size_t)gm * DIM + gn0) = o;
        }
    }
}

// ---------- output GEMV ----------
__global__ __launch_bounds__(256) void out_gemv(const f16* __restrict__ A,
                                                const float* __restrict__ Wout,
                                                const float* __restrict__ bout,
                                                float* __restrict__ out) {
    int wid  = threadIdx.x >> 6;
    int lane = threadIdx.x & 63;
    int row  = blockIdx.x * 4 + wid;
    const f16* p = A + (size_t)row * DIM + lane * 16;
    const float* pw = Wout + lane * 16;
    float s = 0.f;
    #pragma unroll
    for (int i = 0; i < 4; ++i) {
        f16x4 h4 = *(const f16x4*)(p + i * 4);
        float4 w4 = *(const float4*)(pw + i * 4);
        s += (float)h4.x * w4.x + (float)h4.y * w4.y + (float)h4.z * w4.z + (float)h4.w * w4.w;
    }
    #pragma unroll
    for (int off = 32; off > 0; off >>= 1)
        s += __shfl_down(s, off);
    if (lane == 0) out[row] = s + bout[0];
}

// ---------- launcher ----------
extern "C" void kernel_launch(void* const* d_in, const int* in_sizes, int n_in,
                              void* d_out, int out_size, void* d_ws, size_t ws_size,
                              hipStream_t stream) {
    const float* x    = (const float*)d_in[0];
    const float* W0   = (const float*)d_in[1];
    const float* b0   = (const float*)d_in[2];
    const float* Wh   = (const float*)d_in[3];
    const float* bh   = (const float*)d_in[4];
    const float* Wout = (const float*)d_in[5];
    const float* bout = (const float*)d_in[6];
    float* out = (float*)d_out;

    f16* ws = (f16*)d_ws;
    f16* Wp = ws;                                  // packed weights, 20 MB
    f16* A0 = Wp + (size_t)NLAYER * DIM * DIM;     // 16 MB
    f16* A1 = A0 + (size_t)NROWS * DIM;            // 16 MB

    conv_weights<<<NLAYER * 2048 / 4, 256, 0, stream>>>(W0, Wh, Wp);
    conv_x<<<NROWS * DIM / 1024, 256, 0, stream>>>(x, A0);

    const f16* in = A0;
    f16* o = A1;
    for (int l = 0; l < NLAYER; ++l) {
        const float* bias = (l == 0) ? b0 : (bh + (size_t)(l - 1) * DIM);
        layer_gemm<<<256, 512, 0, stream>>>(in, Wp + (size_t)l * DIM * DIM, bias, o);
        f16* t = (f16*)in; in = o; o = t;
    }

    out_gemv<<<NROWS / 4, 256, 0, stream>>>(in, Wout, bout, out);
}

// Round 8
// 267.700 us; speedup vs baseline: 1.6656x; 1.1833x over previous
//
#include <hip/hip_runtime.h>
#include <stdint.h>

typedef unsigned short u16;
typedef unsigned int   u32;
typedef _Float16 f16;
typedef __attribute__((ext_vector_type(4))) float    f32x4;
typedef __attribute__((ext_vector_type(8))) _Float16 f16x8;
typedef __attribute__((ext_vector_type(4))) _Float16 f16x4;

#define DIM    1024
#define NROWS  8192
#define NLAYER 10

__device__ __forceinline__ void gl_lds16(const void* g, void* l) {
    __builtin_amdgcn_global_load_lds((const __attribute__((address_space(1))) u32*)g,
                                     (__attribute__((address_space(3))) u32*)l, 16, 0, 0);
}

// ---------- merged conversion: weights f32->f16 and x f32->f16, one dispatch ----------
#define WELEMS (NLAYER * DIM * DIM)   // 10485760
#define XELEMS (NROWS * DIM)          // 8388608
__global__ __launch_bounds__(256) void conv_all(const float* __restrict__ x,
                                                const float* __restrict__ W0,
                                                const float* __restrict__ Wh,
                                                f16* __restrict__ Wf,
                                                f16* __restrict__ A0) {
    size_t i = ((size_t)blockIdx.x * 256 + threadIdx.x) * 4;
    const float* src;
    f16* dst;
    if (i < WELEMS) {
        src = (i < DIM * DIM) ? (W0 + i) : (Wh + (i - DIM * DIM));
        dst = Wf + i;
    } else {
        size_t k = i - WELEMS;   // < XELEMS
        src = x + k;
        dst = A0 + k;
    }
    float4 w = *(const float4*)src;
    f16x4 o;
    o.x = (f16)w.x; o.y = (f16)w.y; o.z = (f16)w.z; o.w = (f16)w.w;
    *(f16x4*)dst = o;
}

// ---------- fused layer: C = A(8192xK) * W^T + bias, sigmoid -> f16 ----------
// BM=128 BN=128 BK=64, 256 threads = 4 waves (2M x 2N), 64x64/wave, f16 MFMA.
// SINGLE 32 KB LDS buffer -> 4 blocks/CU (128 KB/CU), 16 waves/CU = 4/SIMD.
// Cross-block anti-phase covers stage latency + barrier drains (m97/m114
// mechanism). Schedule per K-tile: stage -> __syncthreads -> compute -> __syncthreads.
#define ABUF_B 0        // [128][64] f16 = 16 KB
#define BBUF_B 16384    // [128][64] f16 = 16 KB
#define NKT    16

__global__ __launch_bounds__(256, 4) void layer_gemm(
        const f16* __restrict__ A,
        const f16* __restrict__ Bg,
        const float* __restrict__ bias,
        f16* __restrict__ O) {
    __shared__ char lds[32768];   // 32 KB single buffer

    // XCD-aware bijective swizzle: 512 blocks, 8 XCDs, 64/XCD
    int bid = blockIdx.x;
    int swz = (bid & 7) * 64 + (bid >> 3);
    int bn = swz & 7;    // 0..7
    int bm = swz >> 3;   // 0..63

    const int tid  = threadIdx.x;
    const int lane = tid & 63;
    const int wid  = tid >> 6;   // 0..3
    const int wr   = wid >> 1;   // 0..1
    const int wc   = wid & 1;    // 0..1

    // ---- staging: 32 chunks of 1KB (8 rows x 128B) per K-tile, 8 per wave ----
    // pre-swizzled global source; logical (row r, colbyte cb) at LDS r*128 + (cb ^ ((r&7)<<4))
    const int swcol = (((lane & 7) ^ ((lane >> 3) & 7)) << 4);
    const char* gsrc[8];
    u32 ldst[8];
    #pragma unroll
    for (int j = 0; j < 8; ++j) {
        int c = wid * 8 + j;
        if (c < 16) {                       // A chunks
            int grow = bm * 128 + c * 8 + (lane >> 3);
            gsrc[j] = (const char*)A + (size_t)grow * 2048 + swcol;
            ldst[j] = ABUF_B + c * 1024;
        } else {                            // B chunks
            int c2 = c - 16;
            int grow = bn * 128 + c2 * 8 + (lane >> 3);
            gsrc[j] = (const char*)Bg + (size_t)grow * 2048 + swcol;
            ldst[j] = BBUF_B + c2 * 1024;
        }
    }

    f32x4 acc[4][4];
    #pragma unroll
    for (int mf = 0; mf < 4; ++mf)
        #pragma unroll
        for (int nf = 0; nf < 4; ++nf)
            acc[mf][nf] = (f32x4){0.f, 0.f, 0.f, 0.f};

    for (int kt = 0; kt < NKT; ++kt) {
        // stage this K-tile (other co-resident blocks compute meanwhile)
        #pragma unroll
        for (int j = 0; j < 8; ++j)
            gl_lds16(gsrc[j] + (size_t)kt * 128, lds + ldst[j]);
        __syncthreads();   // vmcnt drain + barrier; covered by other blocks

        #pragma unroll
        for (int ks = 0; ks < 2; ++ks) {
            f16x8 a[4], b[4];
            const int cb = ks * 64 + ((lane >> 4) << 4);
            #pragma unroll
            for (int mf = 0; mf < 4; ++mf) {
                int r = wr * 64 + mf * 16 + (lane & 15);
                int byt = r * 128 + (cb ^ ((r & 7) << 4));
                a[mf] = *(const f16x8*)(lds + ABUF_B + byt);
            }
            #pragma unroll
            for (int nf = 0; nf < 4; ++nf) {
                int r = wc * 64 + nf * 16 + (lane & 15);
                int byt = r * 128 + (cb ^ ((r & 7) << 4));
                b[nf] = *(const f16x8*)(lds + BBUF_B + byt);
            }
            __builtin_amdgcn_s_setprio(1);
            #pragma unroll
            for (int mf = 0; mf < 4; ++mf)
                #pragma unroll
                for (int nf = 0; nf < 4; ++nf)
                    // swapped operands -> C^T layout (lane holds 4 consecutive cols)
                    acc[mf][nf] = __builtin_amdgcn_mfma_f32_16x16x32_f16(b[nf], a[mf], acc[mf][nf], 0, 0, 0);
            __builtin_amdgcn_s_setprio(0);
        }
        __syncthreads();   // all reads done before next stage overwrites
    }

    // ---- epilogue: bias + sigmoid -> f16, 8B vector stores ----
    // swapped layout: lane holds rows gm = mf*16+(lane&15), cols gn0..gn0+3
    #pragma unroll
    for (int nf = 0; nf < 4; ++nf) {
        int gn0 = bn * 128 + wc * 64 + nf * 16 + ((lane >> 4) << 2);
        f32x4 b4 = *(const f32x4*)(bias + gn0);
        #pragma unroll
        for (int mf = 0; mf < 4; ++mf) {
            int gm = bm * 128 + wr * 64 + mf * 16 + (lane & 15);
            f16x4 o;
            #pragma unroll
            for (int j = 0; j < 4; ++j) {
                float z = acc[mf][nf][j] + b4[j];
                o[j] = (f16)(1.0f / (1.0f + __expf(-z)));
            }
            *(f16x4*)(O + (size_t)gm * DIM + gn0) = o;
        }
    }
}

// ---------- output GEMV ----------
__global__ __launch_bounds__(256) void out_gemv(const f16* __restrict__ A,
                                                const float* __restrict__ Wout,
                                                const float* __restrict__ bout,
                                                float* __restrict__ out) {
    int wid  = threadIdx.x >> 6;
    int lane = threadIdx.x & 63;
    int row  = blockIdx.x * 4 + wid;
    const f16* p = A + (size_t)row * DIM + lane * 16;
    const float* pw = Wout + lane * 16;
    float s = 0.f;
    #pragma unroll
    for (int i = 0; i < 4; ++i) {
        f16x4 h4 = *(const f16x4*)(p + i * 4);
        float4 w4 = *(const float4*)(pw + i * 4);
        s += (float)h4.x * w4.x + (float)h4.y * w4.y + (float)h4.z * w4.z + (float)h4.w * w4.w;
    }
    #pragma unroll
    for (int off = 32; off > 0; off >>= 1)
        s += __shfl_down(s, off);
    if (lane == 0) out[row] = s + bout[0];
}

// ---------- launcher ----------
extern "C" void kernel_launch(void* const* d_in, const int* in_sizes, int n_in,
                              void* d_out, int out_size, void* d_ws, size_t ws_size,
                              hipStream_t stream) {
    const float* x    = (const float*)d_in[0];
    const float* W0   = (const float*)d_in[1];
    const float* b0   = (const float*)d_in[2];
    const float* Wh   = (const float*)d_in[3];
    const float* bh   = (const float*)d_in[4];
    const float* Wout = (const float*)d_in[5];
    const float* bout = (const float*)d_in[6];
    float* out = (float*)d_out;

    f16* ws = (f16*)d_ws;
    f16* Wf = ws;                                  // 20 MB
    f16* A0 = Wf + (size_t)WELEMS;                 // 16 MB
    f16* A1 = A0 + (size_t)XELEMS;                 // 16 MB

    conv_all<<<(WELEMS + XELEMS) / 1024, 256, 0, stream>>>(x, W0, Wh, Wf, A0);

    const f16* in = A0;
    f16* o = A1;
    for (int l = 0; l < NLAYER; ++l) {
        const float* bias = (l == 0) ? b0 : (bh + (size_t)(l - 1) * DIM);
        layer_gemm<<<512, 256, 0, stream>>>(in, Wf + (size_t)l * DIM * DIM, bias, o);
        f16* t = (f16*)in; in = o; o = t;
    }

    out_gemv<<<NROWS / 4, 256, 0, stream>>>(in, Wout, bout, out);
}

// Round 9
// 251.635 us; speedup vs baseline: 1.7720x; 1.0638x over previous
//
#include <hip/hip_runtime.h>
#include <stdint.h>

typedef unsigned int u32;
typedef _Float16 f16;
typedef __attribute__((ext_vector_type(16))) float    f32x16;
typedef __attribute__((ext_vector_type(4)))  float    f32x4;
typedef __attribute__((ext_vector_type(8)))  _Float16 f16x8;
typedef __attribute__((ext_vector_type(4)))  _Float16 f16x4;

#define DIM    1024
#define NROWS  8192
#define NLAYER 10

// ---------- weight packer: f32 W -> MFMA-fragment-ordered f16 chunks ----------
// Chunk (l, c32, kc): 1 KB. Lane holds A-operand frag of v_mfma_f32_32x32x16_f16:
//   W[c32*32 + (lane&31)][kc*16 + (lane>>5)*8 + j], j=0..7  (16 B per lane)
// addr = ((l*32 + c32)*64 + kc)*1024 + lane*16
__global__ __launch_bounds__(256) void pack_weights(const float* __restrict__ W0,
                                                    const float* __restrict__ Wh,
                                                    f16* __restrict__ Wp) {
    int g    = blockIdx.x * 4 + (threadIdx.x >> 6);   // wave id = chunk id, 20480 total
    int lane = threadIdx.x & 63;
    int l    = g >> 11;
    int c32  = (g >> 6) & 31;
    int kc   = g & 63;
    int n  = c32 * 32 + (lane & 31);
    int k  = kc * 16 + (lane >> 5) * 8;
    const float* src = (l == 0 ? W0 : Wh + (size_t)(l - 1) * DIM * DIM) + (size_t)n * DIM + k;
    float4 w0 = *(const float4*)src;
    float4 w1 = *(const float4*)(src + 4);
    f16x8 o;
    o[0] = (f16)w0.x; o[1] = (f16)w0.y; o[2] = (f16)w0.z; o[3] = (f16)w0.w;
    o[4] = (f16)w1.x; o[5] = (f16)w1.y; o[6] = (f16)w1.z; o[7] = (f16)w1.w;
    *(f16x8*)((char*)Wp + (size_t)g * 1024 + lane * 16) = o;
}

// ---------- persistent row-local chain: 10 layers + gemv, zero grid sync ----------
// 256 blocks x 512 threads (8 waves). Block owns rows r0..r0+31. h double-buffered
// in LDS (2 x 64 KB, XOR-swizzled (r&7)<<4). Wave w computes cols [w*128,+128):
// W streams global->reg (L2-hot fragment chunks), h-frag from LDS, 4x 32x32x16
// MFMA per k-step, no barriers inside the k-loop; one __syncthreads per layer.
__global__ __launch_bounds__(512, 2) void mono_chain(
        const float* __restrict__ x,
        const f16* __restrict__ Wp,
        const float* __restrict__ b0,
        const float* __restrict__ bh,
        const float* __restrict__ Wout,
        const float* __restrict__ bout,
        float* __restrict__ out) {
    __shared__ char lds[2 * 65536];   // two h buffers: [32][1024] f16, swizzled

    const int tid  = threadIdx.x;
    const int lane = tid & 63;
    const int wid  = tid >> 6;        // 0..7
    const int bid  = blockIdx.x;
    const int r0   = bid * 32;

    // ---- stage x rows -> buf0 (f32 -> f16, swizzled); fully coalesced float4 ----
    {
        const float* xs = x + (size_t)r0 * DIM;
        #pragma unroll
        for (int it = 0; it < 16; ++it) {
            int f = it * 2048 + tid * 4;          // 0..32767 flat over [32][1024]
            float4 v = *(const float4*)(xs + f);
            f16x4 o;
            o.x = (f16)v.x; o.y = (f16)v.y; o.z = (f16)v.z; o.w = (f16)v.w;
            int r  = f >> 10;
            int kb = (f & 1023) * 2;
            *(f16x4*)(lds + r * 2048 + (kb ^ ((r & 7) << 4))) = o;
        }
    }
    __syncthreads();

    const int c0    = wid * 128;
    const int arow  = (lane & 31) * 2048;        // h row byte base (B-operand: n = lane&31)
    const int ahalf = (lane >> 5) * 16;          // k-half byte offset
    const int aslot = ((lane & 31) & 7) << 4;    // XOR swizzle slot

    int curbuf = 0;
    for (int l = 0; l < NLAYER; ++l) {
        const char* wbase = (const char*)Wp + (size_t)l * 2097152
                          + (size_t)(wid * 4) * 65536 + lane * 16;
        const char* hb = lds + curbuf * 65536;
        char*       hn = lds + (curbuf ^ 1) * 65536;

        f32x16 acc[4];
        #pragma unroll
        for (int nf = 0; nf < 4; ++nf) acc[nf] = (f32x16)(0.f);

        // register double-buffer: W frags (global, L2-hot) + h frag (LDS)
        f16x8 bA[4], aA;
        #pragma unroll
        for (int nf = 0; nf < 4; ++nf)
            bA[nf] = *(const f16x8*)(wbase + nf * 65536);
        aA = *(const f16x8*)(hb + arow + (ahalf ^ aslot));

        #pragma unroll 2
        for (int kc = 0; kc < 64; ++kc) {
            int nk = (kc + 1) & 63;               // wrap: last prefetch re-reads kc=0 (harmless)
            f16x8 bN[4], aN;
            #pragma unroll
            for (int nf = 0; nf < 4; ++nf)
                bN[nf] = *(const f16x8*)(wbase + nf * 65536 + (size_t)nk * 1024);
            aN = *(const f16x8*)(hb + arow + ((nk * 32 + ahalf) ^ aslot));

            __builtin_amdgcn_s_setprio(1);
            #pragma unroll
            for (int nf = 0; nf < 4; ++nf)
                // D = W_frag(MxK, m=out col) * h_frag(KxN, n=row) + acc
                acc[nf] = __builtin_amdgcn_mfma_f32_32x32x16_f16(bA[nf], aA, acc[nf], 0, 0, 0);
            __builtin_amdgcn_s_setprio(0);

            #pragma unroll
            for (int nf = 0; nf < 4; ++nf) bA[nf] = bN[nf];
            aA = aN;
        }

        // ---- epilogue: bias + sigmoid -> f16 into h_next (LDS) ----
        // D layout (m74/m101): col(n)=lane&31 = row r; row(m)=(reg&3)+8*(reg>>2)+4*(lane>>5)
        const float* bias = l ? (bh + (size_t)(l - 1) * DIM) : b0;
        const int r  = lane & 31;
        const int rs = (r & 7) << 4;
        #pragma unroll
        for (int nf = 0; nf < 4; ++nf) {
            #pragma unroll
            for (int g2 = 0; g2 < 4; ++g2) {
                int cb = c0 + nf * 32 + g2 * 8 + 4 * (lane >> 5);
                f32x4 bv = *(const f32x4*)(bias + cb);
                f16x4 o;
                #pragma unroll
                for (int j = 0; j < 4; ++j) {
                    float z = acc[nf][g2 * 4 + j] + bv[j];
                    o[j] = (f16)(1.0f / (1.0f + __expf(-z)));
                }
                *(f16x4*)(hn + r * 2048 + ((cb * 2) ^ rs)) = o;
            }
        }
        __syncthreads();     // h_next complete; also drains this block's LDS ops
        curbuf ^= 1;
    }

    // ---- output gemv: h (curbuf) -> out[r0..r0+31]; 16 threads per row ----
    {
        const char* hf  = lds + curbuf * 65536;
        int row = tid >> 4;           // 0..31
        int seg = tid & 15;
        int rs  = (row & 7) << 4;
        float s = 0.f;
        #pragma unroll
        for (int i = 0; i < 8; ++i) {
            int k0 = seg * 64 + i * 8;
            f16x8 h8 = *(const f16x8*)(hf + row * 2048 + ((k0 * 2) ^ rs));
            const float* w = Wout + k0;
            f32x4 w0 = *(const f32x4*)w;
            f32x4 w1 = *(const f32x4*)(w + 4);
            s += (float)h8[0] * w0[0] + (float)h8[1] * w0[1]
               + (float)h8[2] * w0[2] + (float)h8[3] * w0[3]
               + (float)h8[4] * w1[0] + (float)h8[5] * w1[1]
               + (float)h8[6] * w1[2] + (float)h8[7] * w1[3];
        }
        #pragma unroll
        for (int off = 8; off > 0; off >>= 1)
            s += __shfl_down(s, off, 16);
        if (seg == 0) out[r0 + row] = s + bout[0];
    }
}

// ---------- launcher ----------
extern "C" void kernel_launch(void* const* d_in, const int* in_sizes, int n_in,
                              void* d_out, int out_size, void* d_ws, size_t ws_size,
                              hipStream_t stream) {
    const float* x    = (const float*)d_in[0];
    const float* W0   = (const float*)d_in[1];
    const float* b0   = (const float*)d_in[2];
    const float* Wh   = (const float*)d_in[3];
    const float* bh   = (const float*)d_in[4];
    const float* Wout = (const float*)d_in[5];
    const float* bout = (const float*)d_in[6];
    float* out = (float*)d_out;

    f16* Wp = (f16*)d_ws;   // 20 MB packed weights

    pack_weights<<<NLAYER * 32 * 64 / 4, 256, 0, stream>>>(W0, Wh, Wp);
    mono_chain<<<NROWS / 32, 512, 0, stream>>>(x, Wp, b0, bh, Wout, bout, out);
}

// Round 10
// 242.612 us; speedup vs baseline: 1.8379x; 1.0372x over previous
//
#include <hip/hip_runtime.h>
#include <stdint.h>

typedef unsigned int u32;
typedef _Float16 f16;
typedef __attribute__((ext_vector_type(16))) float    f32x16;
typedef __attribute__((ext_vector_type(4)))  float    f32x4;
typedef __attribute__((ext_vector_type(8)))  _Float16 f16x8;
typedef __attribute__((ext_vector_type(4)))  _Float16 f16x4;

#define DIM    1024
#define NROWS  8192
#define NLAYER 10

// ---------- weight packer: f32 W -> MFMA-fragment-ordered f16 chunks ----------
// Chunk (l, c32, kc): 1 KB. Lane holds A-operand frag of v_mfma_f32_32x32x16_f16:
//   W[c32*32 + (lane&31)][kc*16 + (lane>>5)*8 + j], j=0..7  (16 B per lane)
__global__ __launch_bounds__(256) void pack_weights(const float* __restrict__ W0,
                                                    const float* __restrict__ Wh,
                                                    f16* __restrict__ Wp) {
    int g    = blockIdx.x * 4 + (threadIdx.x >> 6);   // wave id = chunk id, 20480 total
    int lane = threadIdx.x & 63;
    int l    = g >> 11;
    int c32  = (g >> 6) & 31;
    int kc   = g & 63;
    int n  = c32 * 32 + (lane & 31);
    int k  = kc * 16 + (lane >> 5) * 8;
    const float* src = (l == 0 ? W0 : Wh + (size_t)(l - 1) * DIM * DIM) + (size_t)n * DIM + k;
    float4 w0 = *(const float4*)src;
    float4 w1 = *(const float4*)(src + 4);
    f16x8 o;
    o[0] = (f16)w0.x; o[1] = (f16)w0.y; o[2] = (f16)w0.z; o[3] = (f16)w0.w;
    o[4] = (f16)w1.x; o[5] = (f16)w1.y; o[6] = (f16)w1.z; o[7] = (f16)w1.w;
    *(f16x8*)((char*)Wp + (size_t)g * 1024 + lane * 16) = o;
}

// ---------- persistent row-local chain: 10 layers + gemv ----------
// 256 blocks x 1024 threads (16 waves, 4/SIMD). Block owns 32 rows; h lives in
// LDS in FRAGMENT-LINEAR layout: h[r][k] at byte (k>>4)*1024 +
// (r + 32*((k>>3)&1))*16 + (k&7)*2  -> k-loop ds_read_b128 is addr=kc*1024+lane*16,
// perfectly linear (0 conflicts). Wave w computes cols [w*64,+64): 2 MFMA/kc,
// W streams global->reg depth-3 (named slots), no barriers in k-loop.
__global__ __launch_bounds__(1024, 4) void mono_chain(
        const float* __restrict__ x,
        const f16* __restrict__ Wp,
        const float* __restrict__ b0g,
        const float* __restrict__ bh,
        const float* __restrict__ Wout,
        const float* __restrict__ bout,
        float* __restrict__ out) {
    __shared__ char lds[2 * 65536];

    const int tid  = threadIdx.x;
    const int lane = tid & 63;
    const int wid  = tid >> 6;        // 0..15
    const int r0   = blockIdx.x * 32;

    // ---- stage x rows -> buf0 (f32 -> f16, fragment-linear) ----
    {
        const float* xs = x + (size_t)r0 * DIM;
        #pragma unroll
        for (int it = 0; it < 8; ++it) {
            int f = it * 4096 + tid * 4;          // flat r*1024 + k
            float4 v = *(const float4*)(xs + f);
            f16x4 o;
            o.x = (f16)v.x; o.y = (f16)v.y; o.z = (f16)v.z; o.w = (f16)v.w;
            int r = f >> 10, k = f & 1023;
            int addr = (k >> 4) * 1024 + (r + ((k >> 3) & 1) * 32) * 16 + (k & 7) * 2;
            *(f16x4*)(lds + addr) = o;
        }
    }
    __syncthreads();

    int curbuf = 0;
    for (int l = 0; l < NLAYER; ++l) {
        const char* hb = lds + curbuf * 65536;
        char*       hn = lds + (curbuf ^ 1) * 65536;
        // W chunks for this wave: (l*2048 + (wid*2 + nf)*64 + kc)
        const char* w0 = (const char*)Wp + (size_t)l * 2097152
                       + (size_t)(wid * 2) * 65536 + lane * 16;
        const char* w1 = w0 + 65536;
        const char* hL = hb + lane * 16;

        f32x16 acc0 = (f32x16)(0.f), acc1 = (f32x16)(0.f);

        // depth-3 prefetch, named slots (rule #20: no runtime-indexed arrays)
        f16x8 a0, c0_, a1, c1_, a2, c2_, h0, h1, h2;
        a0 = *(const f16x8*)(w0);          c0_ = *(const f16x8*)(w1);
        h0 = *(const f16x8*)(hL);
        a1 = *(const f16x8*)(w0 + 1024);   c1_ = *(const f16x8*)(w1 + 1024);
        h1 = *(const f16x8*)(hL + 1024);
        a2 = *(const f16x8*)(w0 + 2048);   c2_ = *(const f16x8*)(w1 + 2048);
        h2 = *(const f16x8*)(hL + 2048);

#define SUBSTEP(Wa, Wb, Hh, KN)                                                   \
        __builtin_amdgcn_s_setprio(1);                                            \
        acc0 = __builtin_amdgcn_mfma_f32_32x32x16_f16(Wa, Hh, acc0, 0, 0, 0);     \
        acc1 = __builtin_amdgcn_mfma_f32_32x32x16_f16(Wb, Hh, acc1, 0, 0, 0);     \
        __builtin_amdgcn_s_setprio(0);                                            \
        Wa = *(const f16x8*)(w0 + (size_t)(KN) * 1024);                           \
        Wb = *(const f16x8*)(w1 + (size_t)(KN) * 1024);                           \
        Hh = *(const f16x8*)(hL + (size_t)((KN) & 63) * 1024);

        for (int t = 0; t < 21; ++t) {
            SUBSTEP(a0, c0_, h0, 3 * t + 3)
            SUBSTEP(a1, c1_, h1, 3 * t + 4)
            SUBSTEP(a2, c2_, h2, 3 * t + 5)
        }
        // tail: kc = 63 sits in slot 0
        acc0 = __builtin_amdgcn_mfma_f32_32x32x16_f16(a0, h0, acc0, 0, 0, 0);
        acc1 = __builtin_amdgcn_mfma_f32_32x32x16_f16(c0_, h0, acc1, 0, 0, 0);
#undef SUBSTEP

        // ---- epilogue: bias + sigmoid -> f16 into h_next (fragment-linear) ----
        // D layout (m74/m101): n(row r) = lane&31; m(col off) = (reg&3)+8*(reg>>2)+4*(lane>>5)
        const float* bias = l ? (bh + (size_t)(l - 1) * DIM) : b0g;
        const int r    = lane & 31;
        const int hsel = lane >> 5;
        #pragma unroll
        for (int g2 = 0; g2 < 4; ++g2) {
            // nf = 0
            {
                int cb = wid * 64 + g2 * 8 + 4 * hsel;
                f32x4 bv = *(const f32x4*)(bias + cb);
                f16x4 o;
                #pragma unroll
                for (int j = 0; j < 4; ++j) {
                    float z = acc0[g2 * 4 + j] + bv[j];
                    o[j] = (f16)(1.0f / (1.0f + __expf(-z)));
                }
                int chunk = wid * 4 + (g2 >> 1);
                *(f16x4*)(hn + chunk * 1024 + (r + 32 * (g2 & 1)) * 16 + hsel * 8) = o;
            }
            // nf = 1
            {
                int cb = wid * 64 + 32 + g2 * 8 + 4 * hsel;
                f32x4 bv = *(const f32x4*)(bias + cb);
                f16x4 o;
                #pragma unroll
                for (int j = 0; j < 4; ++j) {
                    float z = acc1[g2 * 4 + j] + bv[j];
                    o[j] = (f16)(1.0f / (1.0f + __expf(-z)));
                }
                int chunk = wid * 4 + 2 + (g2 >> 1);
                *(f16x4*)(hn + chunk * 1024 + (r + 32 * (g2 & 1)) * 16 + hsel * 8) = o;
            }
        }
        __syncthreads();     // h_next complete (also drains LDS ops)
        curbuf ^= 1;
    }

    // ---- output gemv: h (buf curbuf) -> out[r0..r0+31]; 32 threads per row ----
    {
        const char* hf = lds + curbuf * 65536;
        int row = tid >> 5;           // 0..31
        int seg = tid & 31;           // k range seg*32 .. +31
        float s = 0.f;
        #pragma unroll
        for (int i = 0; i < 4; ++i) {
            int k0 = seg * 32 + i * 8;
            f16x8 h8 = *(const f16x8*)(hf + (k0 >> 4) * 1024
                                          + (row + 32 * ((k0 >> 3) & 1)) * 16);
            const float* w = Wout + k0;
            f32x4 w0 = *(const f32x4*)w;
            f32x4 w1 = *(const f32x4*)(w + 4);
            s += (float)h8[0] * w0[0] + (float)h8[1] * w0[1]
               + (float)h8[2] * w0[2] + (float)h8[3] * w0[3]
               + (float)h8[4] * w1[0] + (float)h8[5] * w1[1]
               + (float)h8[6] * w1[2] + (float)h8[7] * w1[3];
        }
        #pragma unroll
        for (int off = 16; off > 0; off >>= 1)
            s += __shfl_down(s, off, 32);
        if (seg == 0) out[r0 + row] = s + bout[0];
    }
}

// ---------- launcher ----------
extern "C" void kernel_launch(void* const* d_in, const int* in_sizes, int n_in,
                              void* d_out, int out_size, void* d_ws, size_t ws_size,
                              hipStream_t stream) {
    const float* x    = (const float*)d_in[0];
    const float* W0   = (const float*)d_in[1];
    const float* b0   = (const float*)d_in[2];
    const float* Wh   = (const float*)d_in[3];
    const float* bh   = (const float*)d_in[4];
    const float* Wout = (const float*)d_in[5];
    const float* bout = (const float*)d_in[6];
    float* out = (float*)d_out;

    f16* Wp = (f16*)d_ws;   // 20 MB packed weights

    pack_weights<<<NLAYER * 32 * 64 / 4, 256, 0, stream>>>(W0, Wh, Wp);
    mono_chain<<<NROWS / 32, 1024, 0, stream>>>(x, Wp, b0, bh, Wout, bout, out);
}